// Round 2
// baseline (1064.723 us; speedup 1.0000x reference)
//
#include <hip/hip_runtime.h>

// GRU_27212912787836 : 2-layer GRU, B=512, T=1024, IN=3, H=64
// Inputs/outputs are float32 (per reference). Internal matmuls in bf16 MFMA
// (error budget 7.9e-3 >> expected ~3e-3 drift), cell math + state in fp32.
//
// Round 2: 32 blocks x 4 waves (256 thr). Each block owns 16 batch rows;
// wave jt owns hidden cols [jt*16, jt*16+16) of BOTH layers. Weights
// register-resident as MFMA B-frags (18 frags/wave, fp32->bf16 at init).
// W_ih0 (K=3 zero-padded to 32) B-frags built directly in registers.
// h state fp32 in MFMA D-layout regs; D->A transform via padded bf16 LDS
// tiles (stride 72 -> only 2-way bank aliasing, free). seq_out stored fp32,
// coalesced (16 threads x float4 = 256B per batch row).

typedef __attribute__((ext_vector_type(8))) short short8;   // 8 bf16
typedef __attribute__((ext_vector_type(4))) float floatx4;  // MFMA C/D

#define MFMA16(a, b, c) __builtin_amdgcn_mfma_f32_16x16x32_bf16((a), (b), (c), 0, 0, 0)

static constexpr int kB = 512;
static constexpr int kT = 1024;
static constexpr int kIN = 3;
static constexpr int kH = 64;
static constexpr int LDH = 72;  // padded LDS row stride (bf16 elems)

__device__ __forceinline__ unsigned short f2bf(float f) {
  unsigned u = __builtin_bit_cast(unsigned, f);
  return (unsigned short)((u + 0x7FFFu + ((u >> 16) & 1u)) >> 16);
}
__device__ __forceinline__ float bf2f(unsigned short s) {
  unsigned v = ((unsigned)s) << 16;
  return __builtin_bit_cast(float, v);
}
__device__ __forceinline__ float sigm(float x) {
  return __builtin_amdgcn_rcpf(1.0f + __builtin_amdgcn_exp2f(-1.44269504f * x));
}
__device__ __forceinline__ float tanh_(float x) {
  return 1.0f - 2.0f * __builtin_amdgcn_rcpf(1.0f + __builtin_amdgcn_exp2f(2.88539008f * x));
}
// load 8 consecutive fp32, round to bf16 frag half
__device__ __forceinline__ short8 cvt8(const float* p) {
  short8 f;
#pragma unroll
  for (int j = 0; j < 8; ++j) f[j] = (short)f2bf(p[j]);
  return f;
}

__global__ __launch_bounds__(256, 1) void gru_kernel(
    const float* __restrict__ x,
    const float* __restrict__ Wih0, const float* __restrict__ Whh0,
    const float* __restrict__ bih0, const float* __restrict__ bhh0,
    const float* __restrict__ Wih1, const float* __restrict__ Whh1,
    const float* __restrict__ bih1, const float* __restrict__ bhh1,
    float* __restrict__ out) {
  const int tid  = threadIdx.x;
  const int lane = tid & 63;
  const int jt   = tid >> 6;        // wave id = hidden col tile (0..3)
  const int c    = lane & 15;
  const int grp  = lane >> 4;
  const int wb   = blockIdx.x * 16; // batch base

  __shared__ unsigned short sh_h0[16 * LDH];
  __shared__ unsigned short sh_h1[16 * LDH];

  // ---- register B-frags: [khalf][gate], gate 0=r(nt=jt) 1=z(nt=4+jt) 2=n(nt=8+jt)
  // B-frag: lane holds B[k=grp*8+j][n=nt*16+c] = W[n][k] -> 8 consecutive of row n.
  short8 whh0[2][3], wih1[2][3], whh1[2][3], wx[3];
#pragma unroll
  for (int g = 0; g < 3; ++g) {
    const int nt  = g * 4 + jt;
    const int off = (nt * 16 + c) * kH + grp * 8;
    whh0[0][g] = cvt8(Whh0 + off); whh0[1][g] = cvt8(Whh0 + off + 32);
    wih1[0][g] = cvt8(Wih1 + off); wih1[1][g] = cvt8(Wih1 + off + 32);
    whh1[0][g] = cvt8(Whh1 + off); whh1[1][g] = cvt8(Whh1 + off + 32);
    short8 f = {0, 0, 0, 0, 0, 0, 0, 0};
    if (grp == 0) {  // W_ih0 is (192 x 3): only k=0..2 nonzero
      const float* p = Wih0 + (nt * 16 + c) * kIN;
      f[0] = (short)f2bf(p[0]); f[1] = (short)f2bf(p[1]); f[2] = (short)f2bf(p[2]);
    }
    wx[g] = f;
  }

  // ---- per-lane biases (feature = jt*16 + c) ----
  const int gr = jt * 16 + c, gz = 64 + gr, gn = 128 + gr;
  const float b0r  = bih0[gr] + bhh0[gr];
  const float b0z  = bih0[gz] + bhh0[gz];
  const float b0nx = bih0[gn], b0nh = bhh0[gn];
  const float b1r  = bih1[gr] + bhh1[gr];
  const float b1z  = bih1[gz] + bhh1[gz];
  const float b1nx = bih1[gn], b1nh = bhh1[gn];

  // ---- state ----
  floatx4 h0D = {0.f, 0.f, 0.f, 0.f}, h1D = {0.f, 0.f, 0.f, 0.f};
  short8 h0A[2], h1A[2];
  h0A[0] = h0A[1] = h1A[0] = h1A[1] = short8{0, 0, 0, 0, 0, 0, 0, 0};

  // x A-frag: lane holds A[m=c][k=grp*8+j]; only k<3 nonzero.
  auto load_x = [&](int t) -> short8 {
    short8 f = {0, 0, 0, 0, 0, 0, 0, 0};
    if (grp == 0) {
      const float* p = x + ((size_t)(wb + c) * kT + t) * kIN;
      f[0] = (short)f2bf(p[0]); f[1] = (short)f2bf(p[1]); f[2] = (short)f2bf(p[2]);
    }
    return f;
  };
  short8 xf = load_x(0);

  const int srow  = tid >> 4;         // out-store: batch row 0..15
  const int scol  = (tid & 15) * 4;   // out-store: 4 hidden cols
  const size_t FH = (size_t)kB * kT * kH;

#pragma unroll 1
  for (int t = 0; t < kT; ++t) {
    // ================= layer 0 (9 MFMA) =================
    {
      floatx4 ar  = {b0r, b0r, b0r, b0r};
      floatx4 az  = {b0z, b0z, b0z, b0z};
      floatx4 anx = {b0nx, b0nx, b0nx, b0nx};
      floatx4 anh = {b0nh, b0nh, b0nh, b0nh};
      ar  = MFMA16(xf, wx[0], ar);
      ar  = MFMA16(h0A[0], whh0[0][0], ar);
      ar  = MFMA16(h0A[1], whh0[1][0], ar);
      az  = MFMA16(xf, wx[1], az);
      az  = MFMA16(h0A[0], whh0[0][1], az);
      az  = MFMA16(h0A[1], whh0[1][1], az);
      anx = MFMA16(xf, wx[2], anx);
      anh = MFMA16(h0A[0], whh0[0][2], anh);
      anh = MFMA16(h0A[1], whh0[1][2], anh);
#pragma unroll
      for (int r = 0; r < 4; ++r) {
        float rg = sigm(ar[r]);
        float zg = sigm(az[r]);
        float ng = tanh_(anx[r] + rg * anh[r]);
        float hn = ng + zg * (h0D[r] - ng);
        h0D[r] = hn;
        sh_h0[(grp * 4 + r) * LDH + jt * 16 + c] = f2bf(hn);
      }
    }
    __syncthreads();  // sh_h0(t) complete
    h0A[0] = *(const short8*)(sh_h0 + c * LDH + grp * 8);
    h0A[1] = *(const short8*)(sh_h0 + c * LDH + 32 + grp * 8);
    xf = load_x(t + 1 < kT ? t + 1 : t);  // prefetch next x

    // ================= layer 1 (12 MFMA) =================
    {
      floatx4 ar  = {b1r, b1r, b1r, b1r};
      floatx4 az  = {b1z, b1z, b1z, b1z};
      floatx4 anx = {b1nx, b1nx, b1nx, b1nx};
      floatx4 anh = {b1nh, b1nh, b1nh, b1nh};
      ar  = MFMA16(h0A[0], wih1[0][0], ar);
      ar  = MFMA16(h0A[1], wih1[1][0], ar);
      ar  = MFMA16(h1A[0], whh1[0][0], ar);
      ar  = MFMA16(h1A[1], whh1[1][0], ar);
      az  = MFMA16(h0A[0], wih1[0][1], az);
      az  = MFMA16(h0A[1], wih1[1][1], az);
      az  = MFMA16(h1A[0], whh1[0][1], az);
      az  = MFMA16(h1A[1], whh1[1][1], az);
      anx = MFMA16(h0A[0], wih1[0][2], anx);
      anx = MFMA16(h0A[1], wih1[1][2], anx);
      anh = MFMA16(h1A[0], whh1[0][2], anh);
      anh = MFMA16(h1A[1], whh1[1][2], anh);
#pragma unroll
      for (int r = 0; r < 4; ++r) {
        float rg = sigm(ar[r]);
        float zg = sigm(az[r]);
        float ng = tanh_(anx[r] + rg * anh[r]);
        float hn = ng + zg * (h1D[r] - ng);
        h1D[r] = hn;
        sh_h1[(grp * 4 + r) * LDH + jt * 16 + c] = f2bf(hn);
      }
    }
    __syncthreads();  // sh_h1(t) complete
    h1A[0] = *(const short8*)(sh_h1 + c * LDH + grp * 8);
    h1A[1] = *(const short8*)(sh_h1 + c * LDH + 32 + grp * 8);

    // ---- coalesced fp32 store: 16 threads x float4 = one 256B batch row ----
    {
      const unsigned short* ph = sh_h1 + srow * LDH + scol;
      floatx4 v = {bf2f(ph[0]), bf2f(ph[1]), bf2f(ph[2]), bf2f(ph[3])};
      *(floatx4*)(out + ((size_t)(wb + srow) * kT + t) * kH + scol) = v;
      if (t == kT - 1) {
        *(floatx4*)(out + FH + (size_t)(wb + srow) * kH + scol) = v;
      }
    }
  }
}

extern "C" void kernel_launch(void* const* d_in, const int* in_sizes, int n_in,
                              void* d_out, int out_size, void* d_ws, size_t ws_size,
                              hipStream_t stream) {
  const float* xp   = (const float*)d_in[0];
  const float* wih0 = (const float*)d_in[1];
  const float* whh0 = (const float*)d_in[2];
  const float* bih0 = (const float*)d_in[3];
  const float* bhh0 = (const float*)d_in[4];
  const float* wih1 = (const float*)d_in[5];
  const float* whh1 = (const float*)d_in[6];
  const float* bih1 = (const float*)d_in[7];
  const float* bhh1 = (const float*)d_in[8];
  float* outp = (float*)d_out;
  hipLaunchKernelGGL(gru_kernel, dim3(32), dim3(256), 0, stream,
                     xp, wih0, whh0, bih0, bhh0, wih1, whh1, bih1, bhh1, outp);
}

// Round 3
// 825.040 us; speedup vs baseline: 1.2905x; 1.2905x over previous
//
#include <hip/hip_runtime.h>

// GRU_27212912787836 : 2-layer GRU, B=512, T=1024, IN=3, H=64 (fp32 in/out)
// bf16 MFMA internally, fp32 cell math/state.
//
// Round 3: layer-pipelined, barrier-free. 32 blocks x 8 waves (512 thr).
// Waves 0-3: layer 0 (hidden tile jt); waves 4-7: layer 1 (tile jt).
// h0 stream flows layer0 -> layer1 through an LDS ring (W=8 steps); h1
// exchanged among layer-1 waves via a 2-slot LDS buffer. All sync is
// intra-block LDS acquire/release counters (c0, c1) - NO __syncthreads in
// the loop, so global loads/stores never drain at step boundaries.
// 2 waves/SIMD (one per layer) co-issue -> mutual latency hiding.

typedef __attribute__((ext_vector_type(8))) short short8;   // 8 bf16
typedef __attribute__((ext_vector_type(4))) float floatx4;  // MFMA C/D

#define MFMA16(a, b, c) __builtin_amdgcn_mfma_f32_16x16x32_bf16((a), (b), (c), 0, 0, 0)

static constexpr int kB = 512;
static constexpr int kT = 1024;
static constexpr int kIN = 3;
static constexpr int kH = 64;
static constexpr int LDH = 72;  // padded LDS row stride (bf16): 2-way banks only
static constexpr int W   = 8;   // h0 ring depth (power of 2)

__device__ __forceinline__ unsigned short f2bf(float f) {
  unsigned u = __builtin_bit_cast(unsigned, f);
  return (unsigned short)((u + 0x7FFFu + ((u >> 16) & 1u)) >> 16);
}
__device__ __forceinline__ float bf2f(unsigned short s) {
  unsigned v = ((unsigned)s) << 16;
  return __builtin_bit_cast(float, v);
}
__device__ __forceinline__ float sigm(float x) {
  return __builtin_amdgcn_rcpf(1.0f + __builtin_amdgcn_exp2f(-1.44269504f * x));
}
__device__ __forceinline__ float tanh_(float x) {
  return 1.0f - 2.0f * __builtin_amdgcn_rcpf(1.0f + __builtin_amdgcn_exp2f(2.88539008f * x));
}
__device__ __forceinline__ short8 cvt8(const float* p) {
  short8 f;
#pragma unroll
  for (int j = 0; j < 8; ++j) f[j] = (short)f2bf(p[j]);
  return f;
}

__global__ __launch_bounds__(512, 2) void gru_kernel(
    const float* __restrict__ x,
    const float* __restrict__ Wih0, const float* __restrict__ Whh0,
    const float* __restrict__ bih0, const float* __restrict__ bhh0,
    const float* __restrict__ Wih1, const float* __restrict__ Whh1,
    const float* __restrict__ bih1, const float* __restrict__ bhh1,
    float* __restrict__ out) {
  const int tid  = threadIdx.x;
  const int lane = tid & 63;
  const int jt   = (tid >> 6) & 3;  // hidden tile 0..3
  const int lyr  = tid >> 8;        // 0: layer0 waves, 1: layer1 waves
  const int c    = lane & 15;
  const int grp  = lane >> 4;
  const int wb   = blockIdx.x * 16;

  __shared__ unsigned short ring0[W][16 * LDH];  // h0(t) stream, bf16
  __shared__ unsigned short ring1[2][16 * LDH];  // h1(t) exchange, bf16
  __shared__ unsigned cc[2];                     // step counters: c0, c1 (x4 waves)

  if (tid < 2) cc[tid] = 0;
  __syncthreads();  // once, outside the loop

  auto spin = [&](int i, unsigned tgt) {
    while (__hip_atomic_load(&cc[i], __ATOMIC_ACQUIRE, __HIP_MEMORY_SCOPE_WORKGROUP) < tgt) {}
  };
  auto release = [&](int i) {
    if (lane == 0)
      __hip_atomic_fetch_add(&cc[i], 1u, __ATOMIC_RELEASE, __HIP_MEMORY_SCOPE_WORKGROUP);
  };

  // bias feature index for this lane/tile
  const int gr = jt * 16 + c, gz = 64 + gr, gn = 128 + gr;

  if (lyr == 0) {
    // ================= LAYER-0 stage =================
    short8 whh0[2][3], wx[3];
#pragma unroll
    for (int g = 0; g < 3; ++g) {
      const int off = ((g * 4 + jt) * 16 + c) * kH + grp * 8;
      whh0[0][g] = cvt8(Whh0 + off);
      whh0[1][g] = cvt8(Whh0 + off + 32);
      short8 f = {0, 0, 0, 0, 0, 0, 0, 0};
      if (grp == 0) {  // W_ih0 is (192 x 3), K zero-padded to 32
        const float* p = Wih0 + ((g * 4 + jt) * 16 + c) * kIN;
        f[0] = (short)f2bf(p[0]); f[1] = (short)f2bf(p[1]); f[2] = (short)f2bf(p[2]);
      }
      wx[g] = f;
    }
    const float b0r  = bih0[gr] + bhh0[gr];
    const float b0z  = bih0[gz] + bhh0[gz];
    const float b0nx = bih0[gn], b0nh = bhh0[gn];

    floatx4 h0D = {0.f, 0.f, 0.f, 0.f};
    short8 h0A0 = {0, 0, 0, 0, 0, 0, 0, 0}, h0A1 = h0A0;

    auto load_x = [&](int t) -> short8 {
      short8 f = {0, 0, 0, 0, 0, 0, 0, 0};
      if (grp == 0) {
        const float* p = x + ((size_t)(wb + c) * kT + t) * kIN;
        f[0] = (short)f2bf(p[0]); f[1] = (short)f2bf(p[1]); f[2] = (short)f2bf(p[2]);
      }
      return f;
    };
    short8 xf = load_x(0);

#pragma unroll 1
    for (int t = 0; t < kT; ++t) {
      floatx4 ar  = {b0r, b0r, b0r, b0r};
      floatx4 az  = {b0z, b0z, b0z, b0z};
      floatx4 anx = {b0nx, b0nx, b0nx, b0nx};
      floatx4 anh = {b0nh, b0nh, b0nh, b0nh};
      // x-part first (xf ready long ago), then h-part (h0A freshest)
      ar  = MFMA16(xf, wx[0], ar);
      az  = MFMA16(xf, wx[1], az);
      anx = MFMA16(xf, wx[2], anx);
      ar  = MFMA16(h0A0, whh0[0][0], ar);
      ar  = MFMA16(h0A1, whh0[1][0], ar);
      az  = MFMA16(h0A0, whh0[0][1], az);
      az  = MFMA16(h0A1, whh0[1][1], az);
      anh = MFMA16(h0A0, whh0[0][2], anh);
      anh = MFMA16(h0A1, whh0[1][2], anh);

      short8 xn = load_x(t + 1 < kT ? t + 1 : t);  // global prefetch, off-path

      // ring overwrite guard: slot t%W held step t-W; consumers must be done
      if (t >= W) spin(1, 4u * (t - W + 1));
      unsigned short* slot = ring0[t & (W - 1)];
#pragma unroll
      for (int r = 0; r < 4; ++r) {
        float rg = sigm(ar[r]);
        float zg = sigm(az[r]);
        float ng = tanh_(anx[r] + rg * anh[r]);
        float hn = ng + zg * (h0D[r] - ng);
        h0D[r] = hn;
        slot[(grp * 4 + r) * LDH + jt * 16 + c] = f2bf(hn);
      }
      release(0);
      xf = xn;
      if (t + 1 < kT) {
        spin(0, 4u * (t + 1));  // all 4 l0 waves wrote h0(t)
        h0A0 = *(const short8*)(slot + c * LDH + grp * 8);
        h0A1 = *(const short8*)(slot + c * LDH + 32 + grp * 8);
      }
    }
  } else {
    // ================= LAYER-1 stage =================
    short8 wih1[2][3], whh1[2][3];
#pragma unroll
    for (int g = 0; g < 3; ++g) {
      const int off = ((g * 4 + jt) * 16 + c) * kH + grp * 8;
      wih1[0][g] = cvt8(Wih1 + off);
      wih1[1][g] = cvt8(Wih1 + off + 32);
      whh1[0][g] = cvt8(Whh1 + off);
      whh1[1][g] = cvt8(Whh1 + off + 32);
    }
    const float b1r  = bih1[gr] + bhh1[gr];
    const float b1z  = bih1[gz] + bhh1[gz];
    const float b1nx = bih1[gn], b1nh = bhh1[gn];

    floatx4 h1D = {0.f, 0.f, 0.f, 0.f};
    short8 h1A0 = {0, 0, 0, 0, 0, 0, 0, 0}, h1A1 = h1A0;

    const size_t FH = (size_t)kB * kT * kH;
    float* obase = out + ((size_t)(wb + grp * 4) * kT) * kH + jt * 16 + c;

#pragma unroll 1
    for (int t = 0; t < kT; ++t) {
      floatx4 ar  = {b1r, b1r, b1r, b1r};
      floatx4 az  = {b1z, b1z, b1z, b1z};
      floatx4 anx = {b1nx, b1nx, b1nx, b1nx};
      floatx4 anh = {b1nh, b1nh, b1nh, b1nh};
      // h1-part first: doesn't need the producer, overlaps the spin below
      ar  = MFMA16(h1A0, whh1[0][0], ar);
      ar  = MFMA16(h1A1, whh1[1][0], ar);
      az  = MFMA16(h1A0, whh1[0][1], az);
      az  = MFMA16(h1A1, whh1[1][1], az);
      anh = MFMA16(h1A0, whh1[0][2], anh);
      anh = MFMA16(h1A1, whh1[1][2], anh);

      spin(0, 4u * (t + 1));  // h0(t) fully in ring
      const unsigned short* s0 = ring0[t & (W - 1)];
      short8 h0A0 = *(const short8*)(s0 + c * LDH + grp * 8);
      short8 h0A1 = *(const short8*)(s0 + c * LDH + 32 + grp * 8);
      ar  = MFMA16(h0A0, wih1[0][0], ar);
      ar  = MFMA16(h0A1, wih1[1][0], ar);
      az  = MFMA16(h0A0, wih1[0][1], az);
      az  = MFMA16(h0A1, wih1[1][1], az);
      anx = MFMA16(h0A0, wih1[0][2], anx);
      anx = MFMA16(h0A1, wih1[1][2], anx);

      unsigned short* s1 = ring1[t & 1];
      float hnv[4];
#pragma unroll
      for (int r = 0; r < 4; ++r) {
        float rg = sigm(ar[r]);
        float zg = sigm(az[r]);
        float ng = tanh_(anx[r] + rg * anh[r]);
        float hn = ng + zg * (h1D[r] - ng);
        h1D[r] = hn;
        s1[(grp * 4 + r) * LDH + jt * 16 + c] = f2bf(hn);
        hnv[r] = hn;
      }
      release(1);

      // seq_out straight from registers (off critical path; no barrier drains)
#pragma unroll
      for (int r = 0; r < 4; ++r)
        obase[(size_t)r * kT * kH + (size_t)t * kH] = hnv[r];
      if (t == kT - 1) {
#pragma unroll
        for (int r = 0; r < 4; ++r)
          out[FH + (size_t)(wb + grp * 4 + r) * kH + jt * 16 + c] = hnv[r];
      }

      if (t + 1 < kT) {
        spin(1, 4u * (t + 1));  // all 4 l1 waves wrote h1(t)
        h1A0 = *(const short8*)(s1 + c * LDH + grp * 8);
        h1A1 = *(const short8*)(s1 + c * LDH + 32 + grp * 8);
      }
    }
  }
}

extern "C" void kernel_launch(void* const* d_in, const int* in_sizes, int n_in,
                              void* d_out, int out_size, void* d_ws, size_t ws_size,
                              hipStream_t stream) {
  const float* xp   = (const float*)d_in[0];
  const float* wih0 = (const float*)d_in[1];
  const float* whh0 = (const float*)d_in[2];
  const float* bih0 = (const float*)d_in[3];
  const float* bhh0 = (const float*)d_in[4];
  const float* wih1 = (const float*)d_in[5];
  const float* whh1 = (const float*)d_in[6];
  const float* bih1 = (const float*)d_in[7];
  const float* bhh1 = (const float*)d_in[8];
  float* outp = (float*)d_out;
  hipLaunchKernelGGL(gru_kernel, dim3(32), dim3(512), 0, stream,
                     xp, wih0, whh0, bih0, bhh0, wih1, whh1, bih1, bhh1, outp);
}